// Round 15
// baseline (210.589 us; speedup 1.0000x reference)
//
#include <hip/hip_runtime.h>
#include <math.h>

#define NEG_SLOPE 0.01f
#define NBLK 256        // partition blocks for A1/A2
#define BND  256        // nodes per bucket
#define STB  512        // stats blocks

// bf16 helpers (RNE via bit trick)
__device__ __forceinline__ unsigned short f2b(float f) {
    unsigned int u = __float_as_uint(f);
    u += 0x7FFFu + ((u >> 16) & 1u);
    return (unsigned short)(u >> 16);
}

// ================= CSR build: two-level counting sort, no global atomics ==========

__global__ void partA1(const int* __restrict__ dst, int* __restrict__ cmat,
                       int E, int epb, int nbk) {
    __shared__ int cnt[512];
    for (int i = threadIdx.x; i < 512; i += 512) cnt[i] = 0;
    __syncthreads();
    int b = blockIdx.x;
    int e0 = b * epb, e1 = min(e0 + epb, E);
    for (int e = e0 + threadIdx.x; e < e1; e += 512)
        atomicAdd(&cnt[dst[e] >> 8], 1);          // LDS atomic
    __syncthreads();
    for (int k = threadIdx.x; k < nbk; k += 512)
        cmat[k * NBLK + b] = cnt[k];
}

__global__ void scan_bsum(const int* __restrict__ in, int* __restrict__ bsums, int n) {
    int t = threadIdx.x;
    int i0 = blockIdx.x * 1024 + t * 4;
    int4 c;
    if (i0 + 3 < n) {
        c = *reinterpret_cast<const int4*>(in + i0);
    } else {
        c.x = (i0 + 0 < n) ? in[i0 + 0] : 0;
        c.y = (i0 + 1 < n) ? in[i0 + 1] : 0;
        c.z = (i0 + 2 < n) ? in[i0 + 2] : 0;
        c.w = (i0 + 3 < n) ? in[i0 + 3] : 0;
    }
    int s = c.x + c.y + c.z + c.w;
#pragma unroll
    for (int d = 32; d > 0; d >>= 1) s += __shfl_down(s, d);
    __shared__ int wtot[4];
    if ((t & 63) == 0) wtot[t >> 6] = s;
    __syncthreads();
    if (t == 0) bsums[blockIdx.x] = wtot[0] + wtot[1] + wtot[2] + wtot[3];
}

__global__ void scan_bsums(int* __restrict__ bsums, int* __restrict__ outx, int nb, int n) {
    __shared__ int lds[128];
    int t = threadIdx.x;
    int v = (t < nb) ? bsums[t] : 0;
    lds[t] = v;
    __syncthreads();
    for (int d = 1; d < 128; d <<= 1) {
        int u = (t >= d) ? lds[t - d] : 0;
        __syncthreads();
        lds[t] += u;
        __syncthreads();
    }
    if (t < nb) bsums[t] = lds[t] - v;   // exclusive block base
    if (t == 127) outx[n] = lds[127];    // total (= E)
}

__global__ void scan_excl(const int* __restrict__ in, const int* __restrict__ bbase,
                          int* __restrict__ outx, int n) {
    int t = threadIdx.x;
    int lane = t & 63, wid = t >> 6;
    int i0 = blockIdx.x * 1024 + t * 4;
    int4 c;
    if (i0 + 3 < n) {
        c = *reinterpret_cast<const int4*>(in + i0);
    } else {
        c.x = (i0 + 0 < n) ? in[i0 + 0] : 0;
        c.y = (i0 + 1 < n) ? in[i0 + 1] : 0;
        c.z = (i0 + 2 < n) ? in[i0 + 2] : 0;
        c.w = (i0 + 3 < n) ? in[i0 + 3] : 0;
    }
    int s = c.x + c.y + c.z + c.w;
    int inc = s;
#pragma unroll
    for (int d = 1; d < 64; d <<= 1) {
        int v = __shfl_up(inc, d);
        if (lane >= d) inc += v;
    }
    __shared__ int wtot[4];
    if (lane == 63) wtot[wid] = inc;
    __syncthreads();
    int wbase = 0;
    for (int i = 0; i < wid; ++i) wbase += wtot[i];
    int excl = bbase[blockIdx.x] + wbase + inc - s;
    int o0 = excl, o1 = o0 + c.x, o2 = o1 + c.y, o3 = o2 + c.z;
    if (i0 + 3 < n) {
        *reinterpret_cast<int4*>(outx + i0) = make_int4(o0, o1, o2, o3);
    } else {
        if (i0 + 0 < n) outx[i0 + 0] = o0;
        if (i0 + 1 < n) outx[i0 + 1] = o1;
        if (i0 + 2 < n) outx[i0 + 2] = o2;
        if (i0 + 3 < n) outx[i0 + 3] = o3;
    }
}

// A2: place records into bucket-ordered 'binned' via LDS cursors.
__global__ void partA2(const int* __restrict__ src, const int* __restrict__ dst,
                       const float* __restrict__ w, const int* __restrict__ cbase,
                       int2* __restrict__ binned, int E, int epb, int nbk) {
    __shared__ int cur[512];
    int b = blockIdx.x;
    for (int k = threadIdx.x; k < nbk; k += 512) cur[k] = cbase[k * NBLK + b];
    __syncthreads();
    int e0 = b * epb, e1 = min(e0 + epb, E);
    for (int e = e0 + threadIdx.x; e < e1; e += 512) {
        int d = dst[e];
        int pos = atomicAdd(&cur[d >> 8], 1);     // LDS atomic
        binned[pos] = make_int2(__float_as_int(w[e]), src[e] | ((d & 255) << 18));
    }
}

// B: one block per bucket; per-node LDS count+scan -> offsets; place into csr8 window.
__global__ void partB(const int* __restrict__ cbase, const int2* __restrict__ binned,
                      int2* __restrict__ csr8, int* __restrict__ offsets,
                      int N, int E, int nbk) {
    __shared__ int lcnt[256], lofs[256];
    int b = blockIdx.x;
    int t = threadIdx.x;
    lcnt[t] = 0;
    __syncthreads();
    int bstart = cbase[b * NBLK];
    int bend   = cbase[(b + 1) * NBLK];
    for (int i = bstart + t; i < bend; i += 256)
        atomicAdd(&lcnt[(binned[i].y >> 18) & 255], 1);
    __syncthreads();
    int v = lcnt[t];
    lofs[t] = v;
    __syncthreads();
    for (int d = 1; d < 256; d <<= 1) {
        int u = (t >= d) ? lofs[t - d] : 0;
        __syncthreads();
        lofs[t] += u;
        __syncthreads();
    }
    int excl = lofs[t] - v;
    int node = (b << 8) + t;
    if (node < N) offsets[node] = bstart + excl;
    if (b == nbk - 1 && t == 0) offsets[N] = E;
    __syncthreads();
    lcnt[t] = bstart + excl;
    __syncthreads();
    for (int i = bstart + t; i < bend; i += 256) {
        int2 r = binned[i];
        int pos = atomicAdd(&lcnt[(r.y >> 18) & 255], 1);
        csr8[pos] = make_int2(r.y & 0x3FFFF, r.x);   // (src, w bits)
    }
}

// ---------------- propagate: group-per-row, uint4 gathers, no cross-lane reduce -----
// LPR lanes per row, each lane loads uint4 (8 bf16 cols) -> row = LPR*16B.
// NG = 64/LPR rows per wave. UNR edges in flight per group (MLP depth).
// Each group accumulates its own row in registers; wave loops to its max degree
// with per-group exec-mask predication. out = propagate(in) + bias.

template <int LPR, int UNR, int MINW, bool F32OUT>
__global__ __launch_bounds__(256, MINW) void prop_kernel(
        const uint4* __restrict__ in4, const int* __restrict__ offsets,
        const int2* __restrict__ csr8, const float* __restrict__ bias,
        void* __restrict__ outv, int n) {
    constexpr int NG = 64 / LPR;          // rows per wave
    int wave = (blockIdx.x * 256 + threadIdx.x) >> 6;
    int lane = threadIdx.x & 63;
    int g    = lane / LPR;                // row slot within wave
    int c    = lane % LPR;                // 16B chunk within row
    int row  = wave * NG + g;
    bool valid = row < n;
    int start = 0, end = 0;
    if (valid) { start = offsets[row]; end = offsets[row + 1]; }
    float4 accA = make_float4(0.f, 0.f, 0.f, 0.f);
    float4 accB = make_float4(0.f, 0.f, 0.f, 0.f);
    int i = start;
    int rem = end - start;
    while (__any(rem > 0)) {
        int2  rec[UNR];
        uint4 dat[UNR];
#pragma unroll
        for (int j = 0; j < UNR; ++j) {
            if (j < rem) rec[j] = csr8[i + j];
        }
#pragma unroll
        for (int j = 0; j < UNR; ++j) {
            if (j < rem) dat[j] = in4[(size_t)rec[j].x * LPR + c];
        }
#pragma unroll
        for (int j = 0; j < UNR; ++j) {
            if (j < rem) {
                float w = __int_as_float(rec[j].y);
                accA.x = fmaf(__uint_as_float(dat[j].x << 16),         w, accA.x);
                accA.y = fmaf(__uint_as_float(dat[j].x & 0xFFFF0000u), w, accA.y);
                accA.z = fmaf(__uint_as_float(dat[j].y << 16),         w, accA.z);
                accA.w = fmaf(__uint_as_float(dat[j].y & 0xFFFF0000u), w, accA.w);
                accB.x = fmaf(__uint_as_float(dat[j].z << 16),         w, accB.x);
                accB.y = fmaf(__uint_as_float(dat[j].z & 0xFFFF0000u), w, accB.y);
                accB.z = fmaf(__uint_as_float(dat[j].w << 16),         w, accB.z);
                accB.w = fmaf(__uint_as_float(dat[j].w & 0xFFFF0000u), w, accB.w);
            }
        }
        i   += UNR;
        rem -= UNR;
    }
    if (valid) {
        const float4* b4 = reinterpret_cast<const float4*>(bias);
        float4 ba = b4[c * 2], bb = b4[c * 2 + 1];
        accA.x += ba.x; accA.y += ba.y; accA.z += ba.z; accA.w += ba.w;
        accB.x += bb.x; accB.y += bb.y; accB.z += bb.z; accB.w += bb.w;
        if (F32OUT) {
            float4* o = reinterpret_cast<float4*>(outv) + (size_t)row * LPR * 2;
            o[c * 2]     = accA;
            o[c * 2 + 1] = accB;
        } else {
            uint4 o;
            o.x = (unsigned int)f2b(accA.x) | ((unsigned int)f2b(accA.y) << 16);
            o.y = (unsigned int)f2b(accA.z) | ((unsigned int)f2b(accA.w) << 16);
            o.z = (unsigned int)f2b(accB.x) | ((unsigned int)f2b(accB.y) << 16);
            o.w = (unsigned int)f2b(accB.z) | ((unsigned int)f2b(accB.w) << 16);
            reinterpret_cast<uint4*>(outv)[(size_t)row * LPR + c] = o;
        }
    }
}

// ------- gemm1: g = x(f32) @ W1, bf16 out, no bias -------

__global__ void gemm1_kernel(const float* __restrict__ A, const float* __restrict__ W,
                             unsigned short* __restrict__ out, int n) {
    __shared__ float Wl[64 * 64];
    for (int i = threadIdx.x; i < 64 * 64; i += 256) Wl[i] = W[i];
    __syncthreads();
    int rl = threadIdx.x >> 4;   // 16 rows/block
    int c4 = threadIdx.x & 15;   // 16 col-quads
    int row = blockIdx.x * 16 + rl;
    if (row >= n) return;
    const float4* Ar = reinterpret_cast<const float4*>(A + (size_t)row * 64);
    float4 acc = make_float4(0.f, 0.f, 0.f, 0.f);
#pragma unroll
    for (int k4 = 0; k4 < 16; ++k4) {
        float4 a4 = Ar[k4];
#pragma unroll
        for (int j = 0; j < 4; ++j) {
            float a = (&a4.x)[j];
            const float* wp = &Wl[(k4 * 4 + j) * 64 + c4 * 4];
            acc.x = fmaf(a, wp[0], acc.x);
            acc.y = fmaf(a, wp[1], acc.y);
            acc.z = fmaf(a, wp[2], acc.z);
            acc.w = fmaf(a, wp[3], acc.w);
        }
    }
    unsigned int lo = (unsigned int)f2b(acc.x) | ((unsigned int)f2b(acc.y) << 16);
    unsigned int hi = (unsigned int)f2b(acc.z) | ((unsigned int)f2b(acc.w) << 16);
    reinterpret_cast<uint2*>(out + (size_t)row * 64)[c4] = make_uint2(lo, hi);
}

// ------- gemm_bn<DOUT>: g = lrelu(BN(A;ss)) @ W, bf16 in/out -------

template <int DOUT>
__global__ void gemm_bn(const unsigned short* __restrict__ A, const float* __restrict__ W,
                        const float* __restrict__ ss, unsigned short* __restrict__ out, int n) {
    constexpr int C4  = DOUT / 4;
    constexpr int RPB = 256 / C4;
    __shared__ float Wl[64 * DOUT];
    __shared__ float scl[64], shl[64];
    for (int i = threadIdx.x; i < 64 * DOUT; i += 256) Wl[i] = W[i];
    if (threadIdx.x < 64)       scl[threadIdx.x] = ss[threadIdx.x];
    else if (threadIdx.x < 128) shl[threadIdx.x - 64] = ss[threadIdx.x];
    __syncthreads();
    int rl = threadIdx.x / C4;
    int c4 = threadIdx.x % C4;
    int row = blockIdx.x * RPB + rl;
    if (row >= n) return;
    const uint2* Ar = reinterpret_cast<const uint2*>(A + (size_t)row * 64);
    float4 acc = make_float4(0.f, 0.f, 0.f, 0.f);
#pragma unroll
    for (int k4 = 0; k4 < 16; ++k4) {
        uint2 a2 = Ar[k4];
        float f[4];
        f[0] = __uint_as_float(a2.x << 16);
        f[1] = __uint_as_float(a2.x & 0xFFFF0000u);
        f[2] = __uint_as_float(a2.y << 16);
        f[3] = __uint_as_float(a2.y & 0xFFFF0000u);
#pragma unroll
        for (int j = 0; j < 4; ++j) {
            int kk = k4 * 4 + j;
            float v = fmaf(f[j], scl[kk], shl[kk]);
            v = (v >= 0.f) ? v : NEG_SLOPE * v;
            const float* wp = &Wl[kk * DOUT + c4 * 4];
            acc.x = fmaf(v, wp[0], acc.x);
            acc.y = fmaf(v, wp[1], acc.y);
            acc.z = fmaf(v, wp[2], acc.z);
            acc.w = fmaf(v, wp[3], acc.w);
        }
    }
    unsigned int lo = (unsigned int)f2b(acc.x) | ((unsigned int)f2b(acc.y) << 16);
    unsigned int hi = (unsigned int)f2b(acc.z) | ((unsigned int)f2b(acc.w) << 16);
    reinterpret_cast<uint2*>(out + (size_t)row * DOUT)[c4] = make_uint2(lo, hi);
}

// ------- BN stats over bf16 h: per-block partials -------

__global__ void stats_kernel(const unsigned int* __restrict__ hu, float* __restrict__ part, int n) {
    int t  = threadIdx.x;
    int rg = t >> 5;      // 0..7
    int dw = t & 31;      // dword = cols 2dw, 2dw+1
    float s0 = 0.f, s1 = 0.f, q0 = 0.f, q1 = 0.f;
    for (int r = blockIdx.x * 8 + rg; r < n; r += gridDim.x * 8) {
        unsigned int u = hu[(size_t)r * 32 + dw];
        float v0 = __uint_as_float(u << 16);
        float v1 = __uint_as_float(u & 0xFFFF0000u);
        s0 += v0; q0 += v0 * v0;
        s1 += v1; q1 += v1 * v1;
    }
    __shared__ float ls[8][64], lq[8][64];
    ls[rg][2 * dw]     = s0; lq[rg][2 * dw]     = q0;
    ls[rg][2 * dw + 1] = s1; lq[rg][2 * dw + 1] = q1;
    __syncthreads();
    if (t < 64) {
        float a = 0.f;
        for (int r = 0; r < 8; ++r) a += ls[r][t];
        part[blockIdx.x * 128 + t] = a;
    } else if (t < 128) {
        float a = 0.f;
        for (int r = 0; r < 8; ++r) a += lq[r][t - 64];
        part[blockIdx.x * 128 + t] = a;
    }
}

// ------- BN finalize: parallel partial-reduce, then tiny finalize -------

__global__ void redpart_kernel(const float* __restrict__ part, double* __restrict__ red, int nb) {
    int b = blockIdx.x;
    double acc = 0.0;
    for (int i = threadIdx.x; i < nb; i += 256)
        acc += (double)part[(size_t)i * 128 + b];
#pragma unroll
    for (int d = 32; d > 0; d >>= 1) acc += __shfl_down(acc, d);
    __shared__ double wv[4];
    if ((threadIdx.x & 63) == 0) wv[threadIdx.x >> 6] = acc;
    __syncthreads();
    if (threadIdx.x == 0) red[b] = wv[0] + wv[1] + wv[2] + wv[3];
}

__global__ void bnfin_small(const double* __restrict__ red, const float* __restrict__ g,
                            const float* __restrict__ be, float* __restrict__ ss, int n) {
    int t = threadIdx.x;   // 64
    if (t < 64) {
        double mean = red[t] / n;
        double var  = red[64 + t] / n - mean * mean;
        double inv  = 1.0 / sqrt(var + 1e-5);
        float scale = (float)(inv * (double)g[t]);
        ss[t]      = scale;
        ss[64 + t] = be[t] - (float)mean * scale;
    }
}

// ---------------- launch ----------------

extern "C" void kernel_launch(void* const* d_in, const int* in_sizes, int n_in,
                              void* d_out, int out_size, void* d_ws, size_t ws_size,
                              hipStream_t stream) {
    const float* x    = (const float*)d_in[0];
    const int*   ei   = (const int*)d_in[1];
    const float* ew   = (const float*)d_in[2];
    const float* W1   = (const float*)d_in[4];
    const float* b1   = (const float*)d_in[5];
    const float* g1p  = (const float*)d_in[6];
    const float* be1  = (const float*)d_in[7];
    const float* W2   = (const float*)d_in[8];
    const float* b2   = (const float*)d_in[9];
    const float* g2p  = (const float*)d_in[10];
    const float* be2  = (const float*)d_in[11];
    const float* W3   = (const float*)d_in[12];
    const float* b3   = (const float*)d_in[13];
    float* out = (float*)d_out;

    const int N = in_sizes[0] / 64;   // 100000
    const int E = in_sizes[2];        // 1000000
    const int* src = ei;
    const int* dst = ei + E;

    const int nbk = (N + BND - 1) / BND;        // 391 buckets
    const int M   = nbk * NBLK;                 // cmat elements
    const int epb = (E + NBLK - 1) / NBLK;

    // workspace layout (256B aligned)
    char* wsb = (char*)d_ws;
    size_t off = 0;
    auto alloc = [&](size_t bytes) -> void* {
        off = (off + 255) & ~(size_t)255;
        void* p = wsb + off;
        off += bytes;
        return p;
    };
    unsigned short* g   = (unsigned short*)alloc((size_t)N * 64 * 2);   // 12.8MB, binned alias
    unsigned short* h   = (unsigned short*)alloc((size_t)N * 64 * 2);
    unsigned short* g3  = (unsigned short*)alloc((size_t)N * 32 * 2);
    int2*   csr8    = (int2*)alloc((size_t)E * 8);
    int*    cmat    = (int*)alloc((size_t)M * 4);
    int*    cbase   = (int*)alloc((size_t)(M + 1) * 4);
    int*    offsets = (int*)alloc((size_t)(N + 1) * 4);
    int*    bsums   = (int*)alloc(1024 * 4);
    float*  part    = (float*)alloc((size_t)STB * 128 * 4);
    double* red1    = (double*)alloc(128 * 8);
    double* red2    = (double*)alloc(128 * 8);
    float*  ss1     = (float*)alloc(128 * 4);
    float*  ss2     = (float*)alloc(128 * 4);
    int2*   binned  = (int2*)g;                 // alias g (12.8MB >= E*8); dead before gemm1 writes g
    (void)ws_size; (void)n_in; (void)out_size;

    const int waves64 = (N + 7) / 8;            // prop LPR=8: 8 rows/wave
    const int pb64    = (waves64 * 64 + 255) / 256;
    const int waves32 = (N + 15) / 16;          // prop LPR=4: 16 rows/wave
    const int pb32    = (waves32 * 64 + 255) / 256;
    const int gb16    = (N + 15) / 16;
    const int gb32    = (N + 31) / 32;
    const int nbM     = (M + 1023) / 1024;

    // CSR build (atomic-free counting sort)
    partA1<<<NBLK, 512, 0, stream>>>(dst, cmat, E, epb, nbk);
    scan_bsum<<<nbM, 256, 0, stream>>>(cmat, bsums, M);
    scan_bsums<<<1, 128, 0, stream>>>(bsums, cbase, nbM, M);
    scan_excl<<<nbM, 256, 0, stream>>>(cmat, bsums, cbase, M);
    partA2<<<NBLK, 512, 0, stream>>>(src, dst, ew, cbase, binned, E, epb, nbk);
    partB<<<nbk, 256, 0, stream>>>(cbase, binned, csr8, offsets, N, E, nbk);

    // layer 1: g = x @ W1 ; h1 = propagate(g) + b1 ; stats -> ss1
    gemm1_kernel<<<gb16, 256, 0, stream>>>(x, W1, g, N);
    prop_kernel<8, 8, 6, false><<<pb64, 256, 0, stream>>>((const uint4*)g, offsets, csr8, b1, h, N);
    stats_kernel<<<STB, 256, 0, stream>>>((const unsigned int*)h, part, N);
    redpart_kernel<<<128, 256, 0, stream>>>(part, red1, STB);
    bnfin_small<<<1, 64, 0, stream>>>(red1, g1p, be1, ss1, N);

    // layer 2: g = lrelu(BN(h1)) @ W2 ; h2 = propagate(g) + b2 ; stats -> ss2
    gemm_bn<64><<<gb16, 256, 0, stream>>>(h, W2, ss1, g, N);
    prop_kernel<8, 8, 6, false><<<pb64, 256, 0, stream>>>((const uint4*)g, offsets, csr8, b2, h, N);
    stats_kernel<<<STB, 256, 0, stream>>>((const unsigned int*)h, part, N);
    redpart_kernel<<<128, 256, 0, stream>>>(part, red2, STB);
    bnfin_small<<<1, 64, 0, stream>>>(red2, g2p, be2, ss2, N);

    // layer 3: g3 = lrelu(BN(h2)) @ W3 ; out = propagate(g3) + b3 (f32)
    gemm_bn<32><<<gb32, 256, 0, stream>>>(h, W3, ss2, g3, N);
    prop_kernel<4, 4, 8, true><<<pb32, 256, 0, stream>>>((const uint4*)g3, offsets, csr8, b3, out, N);
}

// Round 16
// 204.073 us; speedup vs baseline: 1.0319x; 1.0319x over previous
//
#include <hip/hip_runtime.h>
#include <math.h>

#define NEG_SLOPE 0.01f
#define NBLK 256        // partition blocks for A1/A2
#define BND  256        // nodes per bucket
#define STB  512        // stats blocks

// bf16 helpers (RNE via bit trick)
__device__ __forceinline__ unsigned short f2b(float f) {
    unsigned int u = __float_as_uint(f);
    u += 0x7FFFu + ((u >> 16) & 1u);
    return (unsigned short)(u >> 16);
}

// ================= CSR build: two-level counting sort, no global atomics ==========

__global__ void partA1(const int* __restrict__ dst, int* __restrict__ cmat,
                       int E, int epb, int nbk) {
    __shared__ int cnt[512];
    for (int i = threadIdx.x; i < 512; i += 512) cnt[i] = 0;
    __syncthreads();
    int b = blockIdx.x;
    int e0 = b * epb, e1 = min(e0 + epb, E);
    for (int e = e0 + threadIdx.x; e < e1; e += 512)
        atomicAdd(&cnt[dst[e] >> 8], 1);          // LDS atomic
    __syncthreads();
    for (int k = threadIdx.x; k < nbk; k += 512)
        cmat[k * NBLK + b] = cnt[k];
}

__global__ void scan_bsum(const int* __restrict__ in, int* __restrict__ bsums, int n) {
    int t = threadIdx.x;
    int i0 = blockIdx.x * 1024 + t * 4;
    int4 c;
    if (i0 + 3 < n) {
        c = *reinterpret_cast<const int4*>(in + i0);
    } else {
        c.x = (i0 + 0 < n) ? in[i0 + 0] : 0;
        c.y = (i0 + 1 < n) ? in[i0 + 1] : 0;
        c.z = (i0 + 2 < n) ? in[i0 + 2] : 0;
        c.w = (i0 + 3 < n) ? in[i0 + 3] : 0;
    }
    int s = c.x + c.y + c.z + c.w;
#pragma unroll
    for (int d = 32; d > 0; d >>= 1) s += __shfl_down(s, d);
    __shared__ int wtot[4];
    if ((t & 63) == 0) wtot[t >> 6] = s;
    __syncthreads();
    if (t == 0) bsums[blockIdx.x] = wtot[0] + wtot[1] + wtot[2] + wtot[3];
}

__global__ void scan_bsums(int* __restrict__ bsums, int* __restrict__ outx, int nb, int n) {
    __shared__ int lds[128];
    int t = threadIdx.x;
    int v = (t < nb) ? bsums[t] : 0;
    lds[t] = v;
    __syncthreads();
    for (int d = 1; d < 128; d <<= 1) {
        int u = (t >= d) ? lds[t - d] : 0;
        __syncthreads();
        lds[t] += u;
        __syncthreads();
    }
    if (t < nb) bsums[t] = lds[t] - v;   // exclusive block base
    if (t == 127) outx[n] = lds[127];    // total (= E)
}

__global__ void scan_excl(const int* __restrict__ in, const int* __restrict__ bbase,
                          int* __restrict__ outx, int n) {
    int t = threadIdx.x;
    int lane = t & 63, wid = t >> 6;
    int i0 = blockIdx.x * 1024 + t * 4;
    int4 c;
    if (i0 + 3 < n) {
        c = *reinterpret_cast<const int4*>(in + i0);
    } else {
        c.x = (i0 + 0 < n) ? in[i0 + 0] : 0;
        c.y = (i0 + 1 < n) ? in[i0 + 1] : 0;
        c.z = (i0 + 2 < n) ? in[i0 + 2] : 0;
        c.w = (i0 + 3 < n) ? in[i0 + 3] : 0;
    }
    int s = c.x + c.y + c.z + c.w;
    int inc = s;
#pragma unroll
    for (int d = 1; d < 64; d <<= 1) {
        int v = __shfl_up(inc, d);
        if (lane >= d) inc += v;
    }
    __shared__ int wtot[4];
    if (lane == 63) wtot[wid] = inc;
    __syncthreads();
    int wbase = 0;
    for (int i = 0; i < wid; ++i) wbase += wtot[i];
    int excl = bbase[blockIdx.x] + wbase + inc - s;
    int o0 = excl, o1 = o0 + c.x, o2 = o1 + c.y, o3 = o2 + c.z;
    if (i0 + 3 < n) {
        *reinterpret_cast<int4*>(outx + i0) = make_int4(o0, o1, o2, o3);
    } else {
        if (i0 + 0 < n) outx[i0 + 0] = o0;
        if (i0 + 1 < n) outx[i0 + 1] = o1;
        if (i0 + 2 < n) outx[i0 + 2] = o2;
        if (i0 + 3 < n) outx[i0 + 3] = o3;
    }
}

// A2: place records into bucket-ordered 'binned' via LDS cursors.
__global__ void partA2(const int* __restrict__ src, const int* __restrict__ dst,
                       const float* __restrict__ w, const int* __restrict__ cbase,
                       int2* __restrict__ binned, int E, int epb, int nbk) {
    __shared__ int cur[512];
    int b = blockIdx.x;
    for (int k = threadIdx.x; k < nbk; k += 512) cur[k] = cbase[k * NBLK + b];
    __syncthreads();
    int e0 = b * epb, e1 = min(e0 + epb, E);
    for (int e = e0 + threadIdx.x; e < e1; e += 512) {
        int d = dst[e];
        int pos = atomicAdd(&cur[d >> 8], 1);     // LDS atomic
        binned[pos] = make_int2(__float_as_int(w[e]), src[e] | ((d & 255) << 18));
    }
}

// B: one block per bucket; per-node LDS count+scan -> offsets; place into csr8 window.
__global__ void partB(const int* __restrict__ cbase, const int2* __restrict__ binned,
                      int2* __restrict__ csr8, int* __restrict__ offsets,
                      int N, int E, int nbk) {
    __shared__ int lcnt[256], lofs[256];
    int b = blockIdx.x;
    int t = threadIdx.x;
    lcnt[t] = 0;
    __syncthreads();
    int bstart = cbase[b * NBLK];
    int bend   = cbase[(b + 1) * NBLK];
    for (int i = bstart + t; i < bend; i += 256)
        atomicAdd(&lcnt[(binned[i].y >> 18) & 255], 1);
    __syncthreads();
    int v = lcnt[t];
    lofs[t] = v;
    __syncthreads();
    for (int d = 1; d < 256; d <<= 1) {
        int u = (t >= d) ? lofs[t - d] : 0;
        __syncthreads();
        lofs[t] += u;
        __syncthreads();
    }
    int excl = lofs[t] - v;
    int node = (b << 8) + t;
    if (node < N) offsets[node] = bstart + excl;
    if (b == nbk - 1 && t == 0) offsets[N] = E;
    __syncthreads();
    lcnt[t] = bstart + excl;
    __syncthreads();
    for (int i = bstart + t; i < bend; i += 256) {
        int2 r = binned[i];
        int pos = atomicAdd(&lcnt[(r.y >> 18) & 255], 1);
        csr8[pos] = make_int2(r.y & 0x3FFFF, r.x);   // (src, w bits)
    }
}

// ---------------- propagate: group-per-row, uint4 gathers, no cross-lane reduce -----
// LPR lanes per row, each lane loads uint4 (8 bf16 cols) -> row = LPR*16B.
// NG = 64/LPR rows per wave; one gather instruction fetches NG rows.
// Each group accumulates its own row in registers; wave loops to its max degree
// with per-group exec-mask predication. out = propagate(in) + bias.

template <int LPR, bool F32OUT>
__global__ __launch_bounds__(256, 8) void prop_kernel(
        const uint4* __restrict__ in4, const int* __restrict__ offsets,
        const int2* __restrict__ csr8, const float* __restrict__ bias,
        void* __restrict__ outv, int n) {
    constexpr int NG = 64 / LPR;          // rows per wave
    int wave = (blockIdx.x * 256 + threadIdx.x) >> 6;
    int lane = threadIdx.x & 63;
    int g    = lane / LPR;                // row slot within wave
    int c    = lane % LPR;                // 16B chunk within row
    int row  = wave * NG + g;
    bool valid = row < n;
    int start = 0, end = 0;
    if (valid) { start = offsets[row]; end = offsets[row + 1]; }
    float4 accA = make_float4(0.f, 0.f, 0.f, 0.f);
    float4 accB = make_float4(0.f, 0.f, 0.f, 0.f);
    int i = start;
    int rem = end - start;
    while (__any(rem > 0)) {
        int2  rec[4];
        uint4 dat[4];
#pragma unroll
        for (int j = 0; j < 4; ++j) {
            if (j < rem) rec[j] = csr8[i + j];
        }
#pragma unroll
        for (int j = 0; j < 4; ++j) {
            if (j < rem) dat[j] = in4[(size_t)rec[j].x * LPR + c];
        }
#pragma unroll
        for (int j = 0; j < 4; ++j) {
            if (j < rem) {
                float w = __int_as_float(rec[j].y);
                accA.x = fmaf(__uint_as_float(dat[j].x << 16),         w, accA.x);
                accA.y = fmaf(__uint_as_float(dat[j].x & 0xFFFF0000u), w, accA.y);
                accA.z = fmaf(__uint_as_float(dat[j].y << 16),         w, accA.z);
                accA.w = fmaf(__uint_as_float(dat[j].y & 0xFFFF0000u), w, accA.w);
                accB.x = fmaf(__uint_as_float(dat[j].z << 16),         w, accB.x);
                accB.y = fmaf(__uint_as_float(dat[j].z & 0xFFFF0000u), w, accB.y);
                accB.z = fmaf(__uint_as_float(dat[j].w << 16),         w, accB.z);
                accB.w = fmaf(__uint_as_float(dat[j].w & 0xFFFF0000u), w, accB.w);
            }
        }
        i   += 4;
        rem -= 4;
    }
    if (valid) {
        const float4* b4 = reinterpret_cast<const float4*>(bias);
        float4 ba = b4[c * 2], bb = b4[c * 2 + 1];
        accA.x += ba.x; accA.y += ba.y; accA.z += ba.z; accA.w += ba.w;
        accB.x += bb.x; accB.y += bb.y; accB.z += bb.z; accB.w += bb.w;
        if (F32OUT) {
            float4* o = reinterpret_cast<float4*>(outv) + (size_t)row * LPR * 2;
            o[c * 2]     = accA;
            o[c * 2 + 1] = accB;
        } else {
            uint4 o;
            o.x = (unsigned int)f2b(accA.x) | ((unsigned int)f2b(accA.y) << 16);
            o.y = (unsigned int)f2b(accA.z) | ((unsigned int)f2b(accA.w) << 16);
            o.z = (unsigned int)f2b(accB.x) | ((unsigned int)f2b(accB.y) << 16);
            o.w = (unsigned int)f2b(accB.z) | ((unsigned int)f2b(accB.w) << 16);
            reinterpret_cast<uint4*>(outv)[(size_t)row * LPR + c] = o;
        }
    }
}

// ------- gemm1: g = x(f32) @ W1, bf16 out, no bias -------

__global__ void gemm1_kernel(const float* __restrict__ A, const float* __restrict__ W,
                             unsigned short* __restrict__ out, int n) {
    __shared__ float Wl[64 * 64];
    for (int i = threadIdx.x; i < 64 * 64; i += 256) Wl[i] = W[i];
    __syncthreads();
    int rl = threadIdx.x >> 4;   // 16 rows/block
    int c4 = threadIdx.x & 15;   // 16 col-quads
    int row = blockIdx.x * 16 + rl;
    if (row >= n) return;
    const float4* Ar = reinterpret_cast<const float4*>(A + (size_t)row * 64);
    float4 acc = make_float4(0.f, 0.f, 0.f, 0.f);
#pragma unroll
    for (int k4 = 0; k4 < 16; ++k4) {
        float4 a4 = Ar[k4];
#pragma unroll
        for (int j = 0; j < 4; ++j) {
            float a = (&a4.x)[j];
            const float* wp = &Wl[(k4 * 4 + j) * 64 + c4 * 4];
            acc.x = fmaf(a, wp[0], acc.x);
            acc.y = fmaf(a, wp[1], acc.y);
            acc.z = fmaf(a, wp[2], acc.z);
            acc.w = fmaf(a, wp[3], acc.w);
        }
    }
    unsigned int lo = (unsigned int)f2b(acc.x) | ((unsigned int)f2b(acc.y) << 16);
    unsigned int hi = (unsigned int)f2b(acc.z) | ((unsigned int)f2b(acc.w) << 16);
    reinterpret_cast<uint2*>(out + (size_t)row * 64)[c4] = make_uint2(lo, hi);
}

// ------- gemm_bn<DOUT>: g = lrelu(BN(A;ss)) @ W, bf16 in/out -------

template <int DOUT>
__global__ void gemm_bn(const unsigned short* __restrict__ A, const float* __restrict__ W,
                        const float* __restrict__ ss, unsigned short* __restrict__ out, int n) {
    constexpr int C4  = DOUT / 4;
    constexpr int RPB = 256 / C4;
    __shared__ float Wl[64 * DOUT];
    __shared__ float scl[64], shl[64];
    for (int i = threadIdx.x; i < 64 * DOUT; i += 256) Wl[i] = W[i];
    if (threadIdx.x < 64)       scl[threadIdx.x] = ss[threadIdx.x];
    else if (threadIdx.x < 128) shl[threadIdx.x - 64] = ss[threadIdx.x];
    __syncthreads();
    int rl = threadIdx.x / C4;
    int c4 = threadIdx.x % C4;
    int row = blockIdx.x * RPB + rl;
    if (row >= n) return;
    const uint2* Ar = reinterpret_cast<const uint2*>(A + (size_t)row * 64);
    float4 acc = make_float4(0.f, 0.f, 0.f, 0.f);
#pragma unroll
    for (int k4 = 0; k4 < 16; ++k4) {
        uint2 a2 = Ar[k4];
        float f[4];
        f[0] = __uint_as_float(a2.x << 16);
        f[1] = __uint_as_float(a2.x & 0xFFFF0000u);
        f[2] = __uint_as_float(a2.y << 16);
        f[3] = __uint_as_float(a2.y & 0xFFFF0000u);
#pragma unroll
        for (int j = 0; j < 4; ++j) {
            int kk = k4 * 4 + j;
            float v = fmaf(f[j], scl[kk], shl[kk]);
            v = (v >= 0.f) ? v : NEG_SLOPE * v;
            const float* wp = &Wl[kk * DOUT + c4 * 4];
            acc.x = fmaf(v, wp[0], acc.x);
            acc.y = fmaf(v, wp[1], acc.y);
            acc.z = fmaf(v, wp[2], acc.z);
            acc.w = fmaf(v, wp[3], acc.w);
        }
    }
    unsigned int lo = (unsigned int)f2b(acc.x) | ((unsigned int)f2b(acc.y) << 16);
    unsigned int hi = (unsigned int)f2b(acc.z) | ((unsigned int)f2b(acc.w) << 16);
    reinterpret_cast<uint2*>(out + (size_t)row * DOUT)[c4] = make_uint2(lo, hi);
}

// ------- BN stats over bf16 h: per-block partials -------

__global__ void stats_kernel(const unsigned int* __restrict__ hu, float* __restrict__ part, int n) {
    int t  = threadIdx.x;
    int rg = t >> 5;      // 0..7
    int dw = t & 31;      // dword = cols 2dw, 2dw+1
    float s0 = 0.f, s1 = 0.f, q0 = 0.f, q1 = 0.f;
    for (int r = blockIdx.x * 8 + rg; r < n; r += gridDim.x * 8) {
        unsigned int u = hu[(size_t)r * 32 + dw];
        float v0 = __uint_as_float(u << 16);
        float v1 = __uint_as_float(u & 0xFFFF0000u);
        s0 += v0; q0 += v0 * v0;
        s1 += v1; q1 += v1 * v1;
    }
    __shared__ float ls[8][64], lq[8][64];
    ls[rg][2 * dw]     = s0; lq[rg][2 * dw]     = q0;
    ls[rg][2 * dw + 1] = s1; lq[rg][2 * dw + 1] = q1;
    __syncthreads();
    if (t < 64) {
        float a = 0.f;
        for (int r = 0; r < 8; ++r) a += ls[r][t];
        part[blockIdx.x * 128 + t] = a;
    } else if (t < 128) {
        float a = 0.f;
        for (int r = 0; r < 8; ++r) a += lq[r][t - 64];
        part[blockIdx.x * 128 + t] = a;
    }
}

// ------- BN finalize: parallel partial-reduce, then tiny finalize -------

__global__ void redpart_kernel(const float* __restrict__ part, double* __restrict__ red, int nb) {
    int b = blockIdx.x;
    double acc = 0.0;
    for (int i = threadIdx.x; i < nb; i += 256)
        acc += (double)part[(size_t)i * 128 + b];
#pragma unroll
    for (int d = 32; d > 0; d >>= 1) acc += __shfl_down(acc, d);
    __shared__ double wv[4];
    if ((threadIdx.x & 63) == 0) wv[threadIdx.x >> 6] = acc;
    __syncthreads();
    if (threadIdx.x == 0) red[b] = wv[0] + wv[1] + wv[2] + wv[3];
}

__global__ void bnfin_small(const double* __restrict__ red, const float* __restrict__ g,
                            const float* __restrict__ be, float* __restrict__ ss, int n) {
    int t = threadIdx.x;   // 64
    if (t < 64) {
        double mean = red[t] / n;
        double var  = red[64 + t] / n - mean * mean;
        double inv  = 1.0 / sqrt(var + 1e-5);
        float scale = (float)(inv * (double)g[t]);
        ss[t]      = scale;
        ss[64 + t] = be[t] - (float)mean * scale;
    }
}

// ---------------- launch ----------------

extern "C" void kernel_launch(void* const* d_in, const int* in_sizes, int n_in,
                              void* d_out, int out_size, void* d_ws, size_t ws_size,
                              hipStream_t stream) {
    const float* x    = (const float*)d_in[0];
    const int*   ei   = (const int*)d_in[1];
    const float* ew   = (const float*)d_in[2];
    const float* W1   = (const float*)d_in[4];
    const float* b1   = (const float*)d_in[5];
    const float* g1p  = (const float*)d_in[6];
    const float* be1  = (const float*)d_in[7];
    const float* W2   = (const float*)d_in[8];
    const float* b2   = (const float*)d_in[9];
    const float* g2p  = (const float*)d_in[10];
    const float* be2  = (const float*)d_in[11];
    const float* W3   = (const float*)d_in[12];
    const float* b3   = (const float*)d_in[13];
    float* out = (float*)d_out;

    const int N = in_sizes[0] / 64;   // 100000
    const int E = in_sizes[2];        // 1000000
    const int* src = ei;
    const int* dst = ei + E;

    const int nbk = (N + BND - 1) / BND;        // 391 buckets
    const int M   = nbk * NBLK;                 // cmat elements
    const int epb = (E + NBLK - 1) / NBLK;

    // workspace layout (256B aligned)
    char* wsb = (char*)d_ws;
    size_t off = 0;
    auto alloc = [&](size_t bytes) -> void* {
        off = (off + 255) & ~(size_t)255;
        void* p = wsb + off;
        off += bytes;
        return p;
    };
    unsigned short* g   = (unsigned short*)alloc((size_t)N * 64 * 2);   // 12.8MB, binned alias
    unsigned short* h   = (unsigned short*)alloc((size_t)N * 64 * 2);
    unsigned short* g3  = (unsigned short*)alloc((size_t)N * 32 * 2);
    int2*   csr8    = (int2*)alloc((size_t)E * 8);
    int*    cmat    = (int*)alloc((size_t)M * 4);
    int*    cbase   = (int*)alloc((size_t)(M + 1) * 4);
    int*    offsets = (int*)alloc((size_t)(N + 1) * 4);
    int*    bsums   = (int*)alloc(1024 * 4);
    float*  part    = (float*)alloc((size_t)STB * 128 * 4);
    double* red1    = (double*)alloc(128 * 8);
    double* red2    = (double*)alloc(128 * 8);
    float*  ss1     = (float*)alloc(128 * 4);
    float*  ss2     = (float*)alloc(128 * 4);
    int2*   binned  = (int2*)g;                 // alias g (12.8MB >= E*8); dead before gemm1 writes g
    (void)ws_size; (void)n_in; (void)out_size;

    const int waves64 = (N + 7) / 8;            // prop LPR=8: 8 rows/wave
    const int pb64    = (waves64 * 64 + 255) / 256;
    const int waves32 = (N + 15) / 16;          // prop LPR=4: 16 rows/wave
    const int pb32    = (waves32 * 64 + 255) / 256;
    const int gb16    = (N + 15) / 16;
    const int gb32    = (N + 31) / 32;
    const int nbM     = (M + 1023) / 1024;

    // CSR build (atomic-free counting sort)
    partA1<<<NBLK, 512, 0, stream>>>(dst, cmat, E, epb, nbk);
    scan_bsum<<<nbM, 256, 0, stream>>>(cmat, bsums, M);
    scan_bsums<<<1, 128, 0, stream>>>(bsums, cbase, nbM, M);
    scan_excl<<<nbM, 256, 0, stream>>>(cmat, bsums, cbase, M);
    partA2<<<NBLK, 512, 0, stream>>>(src, dst, ew, cbase, binned, E, epb, nbk);
    partB<<<nbk, 256, 0, stream>>>(cbase, binned, csr8, offsets, N, E, nbk);

    // layer 1: g = x @ W1 ; h1 = propagate(g) + b1 ; stats -> ss1
    gemm1_kernel<<<gb16, 256, 0, stream>>>(x, W1, g, N);
    prop_kernel<8, false><<<pb64, 256, 0, stream>>>((const uint4*)g, offsets, csr8, b1, h, N);
    stats_kernel<<<STB, 256, 0, stream>>>((const unsigned int*)h, part, N);
    redpart_kernel<<<128, 256, 0, stream>>>(part, red1, STB);
    bnfin_small<<<1, 64, 0, stream>>>(red1, g1p, be1, ss1, N);

    // layer 2: g = lrelu(BN(h1)) @ W2 ; h2 = propagate(g) + b2 ; stats -> ss2
    gemm_bn<64><<<gb16, 256, 0, stream>>>(h, W2, ss1, g, N);
    prop_kernel<8, false><<<pb64, 256, 0, stream>>>((const uint4*)g, offsets, csr8, b2, h, N);
    stats_kernel<<<STB, 256, 0, stream>>>((const unsigned int*)h, part, N);
    redpart_kernel<<<128, 256, 0, stream>>>(part, red2, STB);
    bnfin_small<<<1, 64, 0, stream>>>(red2, g2p, be2, ss2, N);

    // layer 3: g3 = lrelu(BN(h2)) @ W3 ; out = propagate(g3) + b3 (f32)
    gemm_bn<32><<<gb32, 256, 0, stream>>>(h, W3, ss2, g3, N);
    prop_kernel<4, true><<<pb32, 256, 0, stream>>>((const uint4*)g3, offsets, csr8, b3, out, N);
}